// Round 15
// baseline (165.882 us; speedup 1.0000x reference)
//
#include <hip/hip_runtime.h>

#define BATCH 8
#define DIMC 128
#define NTOT 32768
#define HEADS 4
#define DHEAD 32
#define SCALE_Q 0.17677669529663687f
#define GRIDX 64
#define TILES 8   // GRIDX * TILES * 64 == NTOT

typedef _Float16 half8  __attribute__((ext_vector_type(8)));
typedef _Float16 half4v __attribute__((ext_vector_type(4)));
typedef float    f32x4  __attribute__((ext_vector_type(4)));

// workspace byte offsets (all 16B aligned); well under proven ws_size
#define WS_WQKV 0        // _Float16[384*128] = 98304 B (alive through K3: q-rows needed)
#define WS_S    98304    // float[8*4*32*32]  = 131072 B
#define WS_Z    229376   // float[8*4*32]     = 4096 B
#define WS_ST   233472   // float[16]
#define WS_NEED 233600

// d_out layout (rows of 131072 B):
//  G[b] (128x128 f16 = 32 KB) in LOWER half of row b*16 (k2_g writes, K3 reads; K4 overwrites last).
//  y f16 stash in UPPER half of every row (K3 writes, K4 reads row-locally then writes f32).

// ---------------- K0: convert Wqkv to f16, zero accumulators ----------------
__global__ void k0_prep(const float* __restrict__ wqkv, char* __restrict__ ws) {
    int i = blockIdx.x * 256 + threadIdx.x;
    _Float16* Wb = (_Float16*)(ws + WS_WQKV);
    float* S  = (float*)(ws + WS_S);
    float* Z  = (float*)(ws + WS_Z);
    float* St = (float*)(ws + WS_ST);
    if (i < 49152) Wb[i] = (_Float16)wqkv[i];
    int j = i - 49152;
    if (j >= 0 && j < 32768) S[j] = 0.f;
    int k = j - 32768;
    if (k >= 0 && k < 1024) Z[k] = 0.f;
    int m = k - 1024;
    if (m >= 0 && m < 16) St[m] = 0.f;
}

// ---------------- K1: k,v projection -> S = sum exp(k)v^T, Z = sum exp(k) ----------------
// (256,1): avoids the arch-VGPR cap spill (R12 mechanism). Swapped-operand kv-GEMM ->
// vectorized KB/VB writes; Z via ones-MFMA; en-based vb swizzle (R13 fix).
__global__ __launch_bounds__(256, 1) void k1_kv(const float* __restrict__ x,
                                                const _Float16* __restrict__ Wb,
                                                float* __restrict__ S,
                                                float* __restrict__ Z) {
    __shared__ _Float16 Xb[64][136];   // x^T tile: [j][c swizzled]
    __shared__ _Float16 KB[128][64];   // exp(k): [h*32+d][j swizzled]
    __shared__ _Float16 VB[128][64];   // v:      [h*32+e][j swizzled]
    const int t = threadIdx.x;
    const int lane = t & 63, w = t >> 6, g = lane >> 4, l15 = lane & 15;
    const int b = blockIdx.y;

    half8 af[4][4];  // k,v weight frags (rows 128..383), hoisted
#pragma unroll
    for (int mt = 0; mt < 4; ++mt)
#pragma unroll
        for (int kc = 0; kc < 4; ++kc)
            af[mt][kc] = *(const half8*)(Wb + (size_t)(128 + (w * 4 + mt) * 16 + l15) * 128 + kc * 32 + 8 * g);

    half8 vone;
#pragma unroll
    for (int i = 0; i < 8; ++i) vone[i] = (_Float16)1.0f;

    f32x4 sacc[2][2];
#pragma unroll
    for (int dm = 0; dm < 2; ++dm)
#pragma unroll
        for (int en = 0; en < 2; ++en) sacc[dm][en] = (f32x4){0.f, 0.f, 0.f, 0.f};
    f32x4 zacc[2];
    zacc[0] = (f32x4){0.f, 0.f, 0.f, 0.f};
    zacc[1] = (f32x4){0.f, 0.f, 0.f, 0.f};

    const int j4 = t & 15, c0 = t >> 4;
    const int sxw = (j4 & 7) << 3;

    // prologue: load + stage tile 0
    float4 xr[8];
#pragma unroll
    for (int cc = 0; cc < 8; ++cc)
        xr[cc] = *(const float4*)(x + ((size_t)b * DIMC + c0 + 16 * cc) * NTOT + blockIdx.x * 64 + 4 * j4);
#pragma unroll
    for (int cc = 0; cc < 8; ++cc) {
        const int c = c0 + 16 * cc;
        Xb[4 * j4 + 0][c ^ sxw] = (_Float16)xr[cc].x;
        Xb[4 * j4 + 1][c ^ sxw] = (_Float16)xr[cc].y;
        Xb[4 * j4 + 2][c ^ sxw] = (_Float16)xr[cc].z;
        Xb[4 * j4 + 3][c ^ sxw] = (_Float16)xr[cc].w;
    }

    for (int it = 0; it < TILES; ++it) {
        __syncthreads();   // (A) Xb ready; prev KB/VB reads done
        half8 bf[4][4];
#pragma unroll
        for (int nt = 0; nt < 4; ++nt) {
            const int sb = ((4 * nt + (l15 >> 2)) & 7) << 3;
#pragma unroll
            for (int kc = 0; kc < 4; ++kc)
                bf[nt][kc] = *(const half8*)(&Xb[nt * 16 + l15][(kc * 32 + 8 * g) ^ sb]);
        }
        // prefetch next tile (latency hides under kv-GEMM + S/Z)
        if (it < TILES - 1) {
            const int j0n = (blockIdx.x + GRIDX * (it + 1)) * 64;
#pragma unroll
            for (int cc = 0; cc < 8; ++cc)
                xr[cc] = *(const float4*)(x + ((size_t)b * DIMC + c0 + 16 * cc) * NTOT + j0n + 4 * j4);
        }
        // kv-GEMM, swapped operands: lane = 4 consecutive j at one row -> half4v LDS writes
#pragma unroll
        for (int mt = 0; mt < 4; ++mt) {
            f32x4 a0 = (f32x4){0.f,0.f,0.f,0.f}, a1 = a0, a2 = a0, a3 = a0;
#pragma unroll
            for (int kc = 0; kc < 4; ++kc) {
                a0 = __builtin_amdgcn_mfma_f32_16x16x32_f16(bf[0][kc], af[mt][kc], a0, 0, 0, 0);
                a1 = __builtin_amdgcn_mfma_f32_16x16x32_f16(bf[1][kc], af[mt][kc], a1, 0, 0, 0);
                a2 = __builtin_amdgcn_mfma_f32_16x16x32_f16(bf[2][kc], af[mt][kc], a2, 0, 0, 0);
                a3 = __builtin_amdgcn_mfma_f32_16x16x32_f16(bf[3][kc], af[mt][kc], a3, 0, 0, 0);
            }
            const int row16 = (w * 4 + mt) * 16;
            const int sk = ((mt * 4 + (l15 >> 2)) & 7) << 3;
            if (row16 < 128) {
#pragma unroll
                for (int jt = 0; jt < 4; ++jt) {
                    const f32x4 a = (jt == 0) ? a0 : (jt == 1) ? a1 : (jt == 2) ? a2 : a3;
                    half4v p;
#pragma unroll
                    for (int r = 0; r < 4; ++r) p[r] = (_Float16)__expf(a[r]);
                    *(half4v*)(&KB[row16 + l15][(jt * 16 + g * 4) ^ sk]) = p;
                }
            } else {
#pragma unroll
                for (int jt = 0; jt < 4; ++jt) {
                    const f32x4 a = (jt == 0) ? a0 : (jt == 1) ? a1 : (jt == 2) ? a2 : a3;
                    half4v p;
#pragma unroll
                    for (int r = 0; r < 4; ++r) p[r] = (_Float16)a[r];
                    *(half4v*)(&VB[row16 - 128 + l15][(jt * 16 + g * 4) ^ sk]) = p;
                }
            }
        }
        __syncthreads();   // (B) KB/VB ready; Xb reads done
        // restage Xb (overlaps S/Z)
        if (it < TILES - 1) {
#pragma unroll
            for (int cc = 0; cc < 8; ++cc) {
                const int c = c0 + 16 * cc;
                Xb[4 * j4 + 0][c ^ sxw] = (_Float16)xr[cc].x;
                Xb[4 * j4 + 1][c ^ sxw] = (_Float16)xr[cc].y;
                Xb[4 * j4 + 2][c ^ sxw] = (_Float16)xr[cc].z;
                Xb[4 * j4 + 3][c ^ sxw] = (_Float16)xr[cc].w;
            }
        }
        // S/Z accumulate (Z via ones-MFMA; vb swizzle en-based)
#pragma unroll
        for (int dm = 0; dm < 2; ++dm) {
            const int sr = ((4 * dm + (l15 >> 2)) & 7) << 3;
            half8 ka0 = *(const half8*)(&KB[w * 32 + dm * 16 + l15][(8 * g) ^ sr]);
            half8 ka1 = *(const half8*)(&KB[w * 32 + dm * 16 + l15][(32 + 8 * g) ^ sr]);
            zacc[dm] = __builtin_amdgcn_mfma_f32_16x16x32_f16(ka0, vone, zacc[dm], 0, 0, 0);
            zacc[dm] = __builtin_amdgcn_mfma_f32_16x16x32_f16(ka1, vone, zacc[dm], 0, 0, 0);
#pragma unroll
            for (int en = 0; en < 2; ++en) {
                const int se = ((4 * en + (l15 >> 2)) & 7) << 3;
                half8 vb0 = *(const half8*)(&VB[w * 32 + en * 16 + l15][(8 * g) ^ se]);
                half8 vb1 = *(const half8*)(&VB[w * 32 + en * 16 + l15][(32 + 8 * g) ^ se]);
                sacc[dm][en] = __builtin_amdgcn_mfma_f32_16x16x32_f16(ka0, vb0, sacc[dm][en], 0, 0, 0);
                sacc[dm][en] = __builtin_amdgcn_mfma_f32_16x16x32_f16(ka1, vb1, sacc[dm][en], 0, 0, 0);
            }
        }
    }
    if (l15 == 0) {
#pragma unroll
        for (int dm = 0; dm < 2; ++dm)
#pragma unroll
            for (int r = 0; r < 4; ++r)
                atomicAdd(&Z[(b * HEADS + w) * DHEAD + dm * 16 + g * 4 + r], zacc[dm][r]);
    }
#pragma unroll
    for (int dm = 0; dm < 2; ++dm)
#pragma unroll
        for (int en = 0; en < 2; ++en)
#pragma unroll
            for (int r = 0; r < 4; ++r)
                atomicAdd(&S[((size_t)(b * HEADS + w) * DHEAD + dm * 16 + g * 4 + r) * DHEAD + en * 16 + l15],
                          sacc[dm][en][r]);
}

// ---------------- K2g: G[b][o][h*32+d] = sum_e wout[o][h*32+e]*S[b][h][d][e]/Z[b][h][d] ----------------
// Output f16 into d_out row b*16 (lower half). One block per (h, b).
__global__ __launch_bounds__(256) void k2_g(const float* __restrict__ S, const float* __restrict__ Z,
                                            const float* __restrict__ wout, char* __restrict__ ybase) {
    __shared__ float Sd[32][33];
    const int h = blockIdx.x, b = blockIdx.y;
    const int t = threadIdx.x;
    const float* Sb = S + (size_t)(b * HEADS + h) * 1024;
    const float* Zb = Z + (size_t)(b * HEADS + h) * 32;
    for (int i = t; i < 1024; i += 256) {
        int d = i >> 5;
        Sd[d][i & 31] = Sb[i] / Zb[d];
    }
    __syncthreads();
    const int o = t & 127, dh = (t >> 7) * 16;
    float wrow[32];
#pragma unroll
    for (int e = 0; e < 32; ++e) wrow[e] = wout[o * 128 + h * 32 + e];
    _Float16* Gb = (_Float16*)(ybase + (size_t)(b * 16) * 131072);
#pragma unroll
    for (int dd = 0; dd < 16; ++dd) {
        const int d = dh + dd;
        float acc = 0.f;
#pragma unroll
        for (int e = 0; e < 32; ++e) acc = fmaf(wrow[e], Sd[d][e], acc);
        Gb[o * 128 + h * 32 + d] = (_Float16)acc;
    }
}

// ---------------- K3: q proj + softmax + y = G @ Ê + b_out (2 GEMMs, Ê stays in LDS) ----------------
__global__ __launch_bounds__(256, 1) void k3_main(const float* __restrict__ x,
                                                  const _Float16* __restrict__ Wb,
                                                  const float* __restrict__ b_out,
                                                  char* __restrict__ ybase,
                                                  float* __restrict__ St) {
    __shared__ _Float16 Xb[64][136];  // x^T tile
    __shared__ _Float16 qT[64][136];  // Ê: [j][d] (written half4v, read b128 swizzled)
    __shared__ float red[8];
    const int t = threadIdx.x;
    const int lane = t & 63, w = t >> 6, g = lane >> 4, l15 = lane & 15;
    const int b = blockIdx.y;
    const int j4 = t & 15, c0 = t >> 4;
    const int sxw = (j4 & 7) << 3;

    half8 wa[2][4];  // q weight frags (Wb rows 0..127)
    half8 ga[2][4];  // G frags (d_out row b*16 lower half)
    float bo[2][4];
    const _Float16* Gb = (const _Float16*)(ybase + (size_t)(b * 16) * 131072);
#pragma unroll
    for (int mi = 0; mi < 2; ++mi) {
        const int o = (w * 2 + mi) * 16 + l15;
#pragma unroll
        for (int kc = 0; kc < 4; ++kc) {
            wa[mi][kc] = *(const half8*)(Wb + (size_t)o * 128 + kc * 32 + 8 * g);
            ga[mi][kc] = *(const half8*)(Gb + (size_t)o * 128 + kc * 32 + 8 * g);
        }
#pragma unroll
        for (int r = 0; r < 4; ++r) bo[mi][r] = b_out[(w * 2 + mi) * 16 + g * 4 + r];
    }

    float ssum = 0.f, ssq = 0.f;

    // prologue: load + stage tile 0
    float4 xr[8];
#pragma unroll
    for (int cc = 0; cc < 8; ++cc)
        xr[cc] = *(const float4*)(x + ((size_t)b * DIMC + c0 + 16 * cc) * NTOT + blockIdx.x * 64 + 4 * j4);
#pragma unroll
    for (int cc = 0; cc < 8; ++cc) {
        const int c = c0 + 16 * cc;
        Xb[4 * j4 + 0][c ^ sxw] = (_Float16)xr[cc].x;
        Xb[4 * j4 + 1][c ^ sxw] = (_Float16)xr[cc].y;
        Xb[4 * j4 + 2][c ^ sxw] = (_Float16)xr[cc].z;
        Xb[4 * j4 + 3][c ^ sxw] = (_Float16)xr[cc].w;
    }
    __syncthreads();

    for (int it = 0; it < TILES; ++it) {
        const int j0 = (blockIdx.x + GRIDX * it) * 64;
        if (it < TILES - 1) {
            const int j0n = (blockIdx.x + GRIDX * (it + 1)) * 64;
#pragma unroll
            for (int cc = 0; cc < 8; ++cc)
                xr[cc] = *(const float4*)(x + ((size_t)b * DIMC + c0 + 16 * cc) * NTOT + j0n + 4 * j4);
        }
        // phase 2: q-GEMM; E=exp; colsum; Ê = E*SCALE/colsum -> qT[j][d] (half4v)
        {
            half8 bf[4][4];
#pragma unroll
            for (int nt = 0; nt < 4; ++nt) {
                const int sb = ((4 * nt + (l15 >> 2)) & 7) << 3;
#pragma unroll
                for (int kc = 0; kc < 4; ++kc)
                    bf[nt][kc] = *(const half8*)(&Xb[nt * 16 + l15][(kc * 32 + 8 * g) ^ sb]);
            }
            f32x4 eacc[2][4];
#pragma unroll
            for (int mi = 0; mi < 2; ++mi)
#pragma unroll
                for (int nt = 0; nt < 4; ++nt) eacc[mi][nt] = (f32x4){0.f, 0.f, 0.f, 0.f};
#pragma unroll
            for (int mi = 0; mi < 2; ++mi)
#pragma unroll
                for (int kc = 0; kc < 4; ++kc)
#pragma unroll
                    for (int nt = 0; nt < 4; ++nt)
                        eacc[mi][nt] = __builtin_amdgcn_mfma_f32_16x16x32_f16(wa[mi][kc], bf[nt][kc], eacc[mi][nt], 0, 0, 0);
            float ps[4] = {0.f, 0.f, 0.f, 0.f};
#pragma unroll
            for (int mi = 0; mi < 2; ++mi)
#pragma unroll
                for (int nt = 0; nt < 4; ++nt)
#pragma unroll
                    for (int r = 0; r < 4; ++r) {
                        const float e = __expf(eacc[mi][nt][r]);
                        ps[nt] += e;
                        eacc[mi][nt][r] = e;
                    }
            float scn[4];
#pragma unroll
            for (int nt = 0; nt < 4; ++nt) {
                ps[nt] += __shfl_xor(ps[nt], 16);
                ps[nt] += __shfl_xor(ps[nt], 32);
                scn[nt] = SCALE_Q / ps[nt];
            }
#pragma unroll
            for (int mi = 0; mi < 2; ++mi)
#pragma unroll
                for (int nt = 0; nt < 4; ++nt) {
                    half4v p;
#pragma unroll
                    for (int r = 0; r < 4; ++r) p[r] = (_Float16)(eacc[mi][nt][r] * scn[nt]);
                    *(half4v*)(&qT[nt * 16 + l15][((w * 2 + mi) * 16 + g * 4)]) = p;
                }
        }
        __syncthreads();   // (A) qT ready; Xb reads done
        // restage Xb (overlaps phase 3)
        if (it < TILES - 1) {
#pragma unroll
            for (int cc = 0; cc < 8; ++cc) {
                const int c = c0 + 16 * cc;
                Xb[4 * j4 + 0][c ^ sxw] = (_Float16)xr[cc].x;
                Xb[4 * j4 + 1][c ^ sxw] = (_Float16)xr[cc].y;
                Xb[4 * j4 + 2][c ^ sxw] = (_Float16)xr[cc].z;
                Xb[4 * j4 + 3][c ^ sxw] = (_Float16)xr[cc].w;
            }
        }
        // phase 3: y = G @ Ê + b_out -> f16 stash, + stats (qT unswizzled: pad-based [j][d])
        {
            half8 bf[4][4];
#pragma unroll
            for (int nt = 0; nt < 4; ++nt)
#pragma unroll
                for (int kc = 0; kc < 4; ++kc)
                    bf[nt][kc] = *(const half8*)(&qT[nt * 16 + l15][kc * 32 + 8 * g]);
#pragma unroll
            for (int mi = 0; mi < 2; ++mi) {
                const int o0 = (w * 2 + mi) * 16 + g * 4;
                f32x4 acc[4];
#pragma unroll
                for (int nt = 0; nt < 4; ++nt) acc[nt] = (f32x4){0.f, 0.f, 0.f, 0.f};
#pragma unroll
                for (int kc = 0; kc < 4; ++kc)
#pragma unroll
                    for (int nt = 0; nt < 4; ++nt)
                        acc[nt] = __builtin_amdgcn_mfma_f32_16x16x32_f16(ga[mi][kc], bf[nt][kc], acc[nt], 0, 0, 0);
#pragma unroll
                for (int r = 0; r < 4; ++r) {
                    _Float16* yrow = (_Float16*)(ybase + (size_t)(b * DIMC + o0 + r) * 131072 + 65536);
#pragma unroll
                    for (int nt = 0; nt < 4; ++nt) {
                        const float yv = acc[nt][r] + bo[mi][r];
                        ssum += yv;
                        ssq += yv * yv;
                        yrow[j0 + nt * 16 + l15] = (_Float16)yv;
                    }
                }
            }
        }
        __syncthreads();   // (B) qT reads done before next iter's writes; Xb staged
    }
#pragma unroll
    for (int m = 32; m; m >>= 1) { ssum += __shfl_xor(ssum, m); ssq += __shfl_xor(ssq, m); }
    if (lane == 0) { red[w] = ssum; red[4 + w] = ssq; }
    __syncthreads();
    if (t == 0) {
        atomicAdd(&St[b * 2 + 0], red[0] + red[1] + red[2] + red[3]);
        atomicAdd(&St[b * 2 + 1], red[4] + red[5] + red[6] + red[7]);
    }
}

// ---------------- K4: layernorm; read f16 stash (2nd half of own row), write f32 ----------------
__global__ __launch_bounds__(256) void k4_norm(float* __restrict__ out, const float* __restrict__ St,
                                               const float* __restrict__ gamma,
                                               const float* __restrict__ beta) {
    const int o = blockIdx.x;
    const int b = blockIdx.y;
    const int t = threadIdx.x;
    const size_t row = (size_t)b * DIMC + o;
    const float n = (float)DIMC * (float)NTOT;
    const float mean = St[b * 2] / n;
    const float var = St[b * 2 + 1] / n - mean * mean;
    const float rs = rsqrtf(var + 1e-5f);
    const float ga = gamma[o] * rs;
    const float be = beta[o];
    const half8* yh = (const half8*)((const char*)out + row * 131072 + 65536);
    half8 hbuf[16];
#pragma unroll
    for (int i = 0; i < 16; ++i) hbuf[i] = yh[i * 256 + t];
    __syncthreads();  // all reads before any f32 overwrite (stash lives in this row)
    float4* orow = (float4*)(out + row * NTOT);
#pragma unroll
    for (int i = 0; i < 16; ++i) {
        const int e4 = (i * 256 + t) * 2;
        float4 v0, v1;
        v0.x = ((float)hbuf[i][0] - mean) * ga + be;
        v0.y = ((float)hbuf[i][1] - mean) * ga + be;
        v0.z = ((float)hbuf[i][2] - mean) * ga + be;
        v0.w = ((float)hbuf[i][3] - mean) * ga + be;
        v1.x = ((float)hbuf[i][4] - mean) * ga + be;
        v1.y = ((float)hbuf[i][5] - mean) * ga + be;
        v1.z = ((float)hbuf[i][6] - mean) * ga + be;
        v1.w = ((float)hbuf[i][7] - mean) * ga + be;
        orow[e4] = v0;
        orow[e4 + 1] = v1;
    }
}

extern "C" void kernel_launch(void* const* d_in, const int* in_sizes, int n_in,
                              void* d_out, int out_size, void* d_ws, size_t ws_size,
                              hipStream_t stream) {
    const float* x     = (const float*)d_in[0];
    const float* wqkv  = (const float*)d_in[1];
    const float* wout  = (const float*)d_in[2];
    const float* b_out = (const float*)d_in[3];
    const float* gamma = (const float*)d_in[4];
    const float* beta  = (const float*)d_in[5];
    if (ws_size < WS_NEED) return;
    char* ws = (char*)d_ws;
    _Float16* Wb = (_Float16*)(ws + WS_WQKV);
    float* S  = (float*)(ws + WS_S);
    float* Z  = (float*)(ws + WS_Z);
    float* St = (float*)(ws + WS_ST);

    k0_prep<<<325, 256, 0, stream>>>(wqkv, ws);
    k1_kv<<<dim3(GRIDX, 8), 256, 0, stream>>>(x, Wb, S, Z);
    k2_g<<<dim3(HEADS, 8), 256, 0, stream>>>(S, Z, wout, (char*)d_out);
    k3_main<<<dim3(GRIDX, 8), 256, 0, stream>>>(x, Wb, b_out, (char*)d_out, St);
    k4_norm<<<dim3(128, 8), 256, 0, stream>>>((float*)d_out, St, gamma, beta);
}

// Round 16
// 137.452 us; speedup vs baseline: 1.2068x; 1.2068x over previous
//
#include <hip/hip_runtime.h>

#define BATCH 8
#define DIMC 128
#define NTOT 32768
#define HEADS 4
#define DHEAD 32
#define SCALE_Q 0.17677669529663687f
#define GRIDX 64
#define TILES 8   // GRIDX * TILES * 64 == NTOT

typedef _Float16 half8  __attribute__((ext_vector_type(8)));
typedef _Float16 half4v __attribute__((ext_vector_type(4)));
typedef float    f32x4  __attribute__((ext_vector_type(4)));

// workspace byte offsets (all 16B aligned)
#define WS_WQKV 0        // _Float16[384*128]   = 98304 B
#define WS_S    98304    // float[8*4*32*32]    = 131072 B
#define WS_Z    229376   // float[8*4*32]       = 4096 B
#define WS_ST   233472   // float[16]           (64 B)
#define WS_NEED 233536

// G[b] (128x128 f16, 32 KB each) lives in d_out: lower half of row (b>>1), offset (b&1)*32768.
// K3's f16 stash uses the UPPER half of every row; K4 overwrites everything afterwards.

// ---------------- K0: convert Wqkv to f16, zero accumulators ----------------
__global__ void k0_prep(const float* __restrict__ wqkv, char* __restrict__ ws) {
    int i = blockIdx.x * 256 + threadIdx.x;
    _Float16* Wb = (_Float16*)(ws + WS_WQKV);
    float* S  = (float*)(ws + WS_S);
    float* Z  = (float*)(ws + WS_Z);
    float* St = (float*)(ws + WS_ST);
    if (i < 49152) Wb[i] = (_Float16)wqkv[i];
    int j = i - 49152;
    if (j >= 0 && j < 32768) S[j] = 0.f;
    int k = j - 32768;
    if (k >= 0 && k < 1024) Z[k] = 0.f;
    int m = k - 1024;
    if (m >= 0 && m < 16) St[m] = 0.f;
}

// ---------------- K1: k,v projection + S = sum_n exp(k) v^T, Z = sum_n exp(k) ----------------
// R5/R8-proven form: pipelined, float4 row-quad staging, grid (64,8) x 8 tiles, (256,2).
// Single change vs R8: vb read-swizzle is en-based (matches VB's row-based write swizzle);
// the dm-based read paired E[d][j] with V[e][j^32] on off-diagonal quadrants (R13-confirmed,
// absmax 0.047 -> 0.0156).
__global__ __launch_bounds__(256, 2) void k1_kv(const float* __restrict__ x,
                                                const _Float16* __restrict__ Wb,
                                                float* __restrict__ S,
                                                float* __restrict__ Z) {
    __shared__ _Float16 Xb[64][136];   // x^T tile: [j][c swizzled]
    __shared__ _Float16 KB[128][64];   // exp(k): [h*32+d][j swizzled]
    __shared__ _Float16 VB[128][64];   // v:      [h*32+e][j swizzled]
    const int t = threadIdx.x;
    const int lane = t & 63, w = t >> 6, g = lane >> 4, l15 = lane & 15;
    const int b = blockIdx.y;

    half8 af[4][4];
#pragma unroll
    for (int mt = 0; mt < 4; ++mt)
#pragma unroll
        for (int kc = 0; kc < 4; ++kc)
            af[mt][kc] = *(const half8*)(Wb + (size_t)(128 + (w * 4 + mt) * 16 + l15) * 128 + kc * 32 + 8 * g);

    f32x4 sacc[2][2];
#pragma unroll
    for (int dm = 0; dm < 2; ++dm)
#pragma unroll
        for (int en = 0; en < 2; ++en) sacc[dm][en] = (f32x4){0.f, 0.f, 0.f, 0.f};
    float zpart = 0.f;

    const int j4 = t & 15, c0 = t >> 4;
    const int sxw = (j4 & 7) << 3;

    // prologue: load + stage tile 0
    float4 xr[8];
#pragma unroll
    for (int cc = 0; cc < 8; ++cc)
        xr[cc] = *(const float4*)(x + ((size_t)b * DIMC + c0 + 16 * cc) * NTOT + blockIdx.x * 64 + 4 * j4);
#pragma unroll
    for (int cc = 0; cc < 8; ++cc) {
        const int c = c0 + 16 * cc;
        Xb[4 * j4 + 0][c ^ sxw] = (_Float16)xr[cc].x;
        Xb[4 * j4 + 1][c ^ sxw] = (_Float16)xr[cc].y;
        Xb[4 * j4 + 2][c ^ sxw] = (_Float16)xr[cc].z;
        Xb[4 * j4 + 3][c ^ sxw] = (_Float16)xr[cc].w;
    }

    for (int it = 0; it < TILES; ++it) {
        if (it < TILES - 1) {
            const int j0n = (blockIdx.x + GRIDX * (it + 1)) * 64;
#pragma unroll
            for (int cc = 0; cc < 8; ++cc)
                xr[cc] = *(const float4*)(x + ((size_t)b * DIMC + c0 + 16 * cc) * NTOT + j0n + 4 * j4);
        }
        __syncthreads();   // Xb(tile it) visible; prev-iter KB/VB reads done
        half8 bf[4][4];
#pragma unroll
        for (int nt = 0; nt < 4; ++nt) {
            const int sb = ((4 * nt + (l15 >> 2)) & 7) << 3;
#pragma unroll
            for (int kc = 0; kc < 4; ++kc)
                bf[nt][kc] = *(const half8*)(&Xb[nt * 16 + l15][(kc * 32 + 8 * g) ^ sb]);
        }
#pragma unroll
        for (int mt = 0; mt < 4; ++mt) {
            f32x4 a0 = (f32x4){0.f,0.f,0.f,0.f}, a1 = a0, a2 = a0, a3 = a0;
#pragma unroll
            for (int kc = 0; kc < 4; ++kc) {
                a0 = __builtin_amdgcn_mfma_f32_16x16x32_f16(af[mt][kc], bf[0][kc], a0, 0, 0, 0);
                a1 = __builtin_amdgcn_mfma_f32_16x16x32_f16(af[mt][kc], bf[1][kc], a1, 0, 0, 0);
                a2 = __builtin_amdgcn_mfma_f32_16x16x32_f16(af[mt][kc], bf[2][kc], a2, 0, 0, 0);
                a3 = __builtin_amdgcn_mfma_f32_16x16x32_f16(af[mt][kc], bf[3][kc], a3, 0, 0, 0);
            }
            const int lr0 = (w * 4 + mt) * 16 + g * 4;
            const int skv = (((w * 4 + mt) * 4 + g) & 7) << 3;
#pragma unroll
            for (int nt = 0; nt < 4; ++nt) {
                const f32x4 a = (nt == 0) ? a0 : (nt == 1) ? a1 : (nt == 2) ? a2 : a3;
                const int jn = (nt * 16 + l15) ^ skv;
                if (lr0 < 128) {
#pragma unroll
                    for (int r = 0; r < 4; ++r) KB[lr0 + r][jn] = (_Float16)__expf(a[r]);
                } else {
#pragma unroll
                    for (int r = 0; r < 4; ++r) VB[lr0 - 128 + r][jn] = (_Float16)a[r];
                }
            }
        }
        __syncthreads();   // KB/VB ready; Xb reads done
        // stage tile it+1 into Xb, overlapping the S/Z phase
        if (it < TILES - 1) {
#pragma unroll
            for (int cc = 0; cc < 8; ++cc) {
                const int c = c0 + 16 * cc;
                Xb[4 * j4 + 0][c ^ sxw] = (_Float16)xr[cc].x;
                Xb[4 * j4 + 1][c ^ sxw] = (_Float16)xr[cc].y;
                Xb[4 * j4 + 2][c ^ sxw] = (_Float16)xr[cc].z;
                Xb[4 * j4 + 3][c ^ sxw] = (_Float16)xr[cc].w;
            }
        }
#pragma unroll
        for (int dm = 0; dm < 2; ++dm) {
            const int sr = ((4 * dm + (l15 >> 2)) & 7) << 3;
#pragma unroll
            for (int en = 0; en < 2; ++en) {
                const int se = ((4 * en + (l15 >> 2)) & 7) << 3;  // en-based: matches VB write
#pragma unroll
                for (int kc = 0; kc < 2; ++kc) {
                    half8 ka = *(const half8*)(&KB[w * 32 + dm * 16 + l15][(kc * 32 + 8 * g) ^ sr]);
                    half8 vb = *(const half8*)(&VB[w * 32 + en * 16 + l15][(kc * 32 + 8 * g) ^ se]);
                    sacc[dm][en] = __builtin_amdgcn_mfma_f32_16x16x32_f16(ka, vb, sacc[dm][en], 0, 0, 0);
                }
            }
        }
        {
            const int zr = lane >> 1;
            const int sz = ((zr >> 2) & 7) << 3;
#pragma unroll
            for (int s8 = 0; s8 < 4; ++s8) {
                half8 hv = *(const half8*)(&KB[w * 32 + zr][((lane & 1) * 32 + 8 * s8) ^ sz]);
#pragma unroll
                for (int e = 0; e < 8; ++e) zpart += (float)hv[e];
            }
        }
    }
    {
        float zt = zpart + __shfl_xor(zpart, 1);
        if ((lane & 1) == 0) atomicAdd(&Z[(b * HEADS + w) * DHEAD + (lane >> 1)], zt);
    }
#pragma unroll
    for (int dm = 0; dm < 2; ++dm)
#pragma unroll
        for (int en = 0; en < 2; ++en)
#pragma unroll
            for (int r = 0; r < 4; ++r)
                atomicAdd(&S[((size_t)(b * HEADS + w) * DHEAD + dm * 16 + g * 4 + r) * DHEAD + en * 16 + l15],
                          sacc[dm][en][r]);
}

// ---------------- K2g: G[b][o][h*32+d] = sum_e wout[o][h*32+e] * S[b][h][d][e] / Z[b][h][d] ----------------
// One block per (h, b). Output f16 into d_out scratch region (see map above).
__global__ __launch_bounds__(256) void k2_g(const float* __restrict__ S, const float* __restrict__ Z,
                                            const float* __restrict__ wout, char* __restrict__ ybase) {
    __shared__ float Sd[32][33];
    const int h = blockIdx.x, b = blockIdx.y;
    const int t = threadIdx.x;
    const float* Sb = S + (size_t)(b * HEADS + h) * 1024;
    const float* Zb = Z + (size_t)(b * HEADS + h) * 32;
    for (int i = t; i < 1024; i += 256) {
        int d = i >> 5;
        Sd[d][i & 31] = Sb[i] / Zb[d];
    }
    __syncthreads();
    const int o = t & 127, dh = (t >> 7) * 16;
    float wrow[32];
#pragma unroll
    for (int e = 0; e < 32; ++e) wrow[e] = wout[o * 128 + h * 32 + e];
    _Float16* Gb = (_Float16*)(ybase + (size_t)(b >> 1) * 131072 + (size_t)(b & 1) * 32768);
#pragma unroll
    for (int dd = 0; dd < 16; ++dd) {
        const int d = dh + dd;
        float acc = 0.f;
#pragma unroll
        for (int e = 0; e < 32; ++e) acc = fmaf(wrow[e], Sd[d][e], acc);
        Gb[o * 128 + h * 32 + d] = (_Float16)acc;
    }
}

// ---------------- K3: pipelined q proj + fused softmax-scale + y = G @ Ê (f16 stash) + stats ----------------
// 2 GEMM phases, 2 barriers/iter. G A-frags loop-invariant in registers.
__global__ __launch_bounds__(256, 2) void k3_main(const float* __restrict__ x,
                                                  const _Float16* __restrict__ Wb,
                                                  const float* __restrict__ b_out,
                                                  char* __restrict__ ybase,
                                                  float* __restrict__ St) {
    __shared__ _Float16 Xb[64][136];  // x^T tile
    __shared__ _Float16 qT[64][136];  // Ê = exp(q)*scl: [j][d]
    __shared__ float red[8];
    const int t = threadIdx.x;
    const int lane = t & 63, w = t >> 6, g = lane >> 4, l15 = lane & 15;
    const int b = blockIdx.y;
    const int j4 = t & 15, c0 = t >> 4;
    const int sxw = (j4 & 7) << 3;

    // loop-invariant register fragments
    half8 wa[2][4];  // q-projection A-frags (Wb rows 0..127)
    half8 ga[2][4];  // y-GEMM A-frags (G rows)
    const _Float16* Gb = (const _Float16*)(ybase + (size_t)(b >> 1) * 131072 + (size_t)(b & 1) * 32768);
#pragma unroll
    for (int mi = 0; mi < 2; ++mi)
#pragma unroll
        for (int kc = 0; kc < 4; ++kc) {
            wa[mi][kc] = *(const half8*)(Wb + (size_t)((w * 2 + mi) * 16 + l15) * 128 + kc * 32 + 8 * g);
            ga[mi][kc] = *(const half8*)(Gb + (size_t)((w * 2 + mi) * 16 + l15) * 128 + kc * 32 + 8 * g);
        }

    float ssum = 0.f, ssq = 0.f;

    // prologue: load + stage tile 0
    float4 xr[8];
#pragma unroll
    for (int cc = 0; cc < 8; ++cc)
        xr[cc] = *(const float4*)(x + ((size_t)b * DIMC + c0 + 16 * cc) * NTOT + blockIdx.x * 64 + 4 * j4);
#pragma unroll
    for (int cc = 0; cc < 8; ++cc) {
        const int c = c0 + 16 * cc;
        Xb[4 * j4 + 0][c ^ sxw] = (_Float16)xr[cc].x;
        Xb[4 * j4 + 1][c ^ sxw] = (_Float16)xr[cc].y;
        Xb[4 * j4 + 2][c ^ sxw] = (_Float16)xr[cc].z;
        Xb[4 * j4 + 3][c ^ sxw] = (_Float16)xr[cc].w;
    }
    __syncthreads();

    for (int it = 0; it < TILES; ++it) {
        const int j0 = (blockIdx.x + GRIDX * it) * 64;
        if (it < TILES - 1) {
            const int j0n = (blockIdx.x + GRIDX * (it + 1)) * 64;
#pragma unroll
            for (int cc = 0; cc < 8; ++cc)
                xr[cc] = *(const float4*)(x + ((size_t)b * DIMC + c0 + 16 * cc) * NTOT + j0n + 4 * j4);
        }
        // phase 2: q GEMM from Xb; E=exp; colsum reduce; write Ê = E*scl -> qT
        {
            half8 bf[4][4];
#pragma unroll
            for (int nt = 0; nt < 4; ++nt) {
                const int sb = ((4 * nt + (l15 >> 2)) & 7) << 3;
#pragma unroll
                for (int kc = 0; kc < 4; ++kc)
                    bf[nt][kc] = *(const half8*)(&Xb[nt * 16 + l15][(kc * 32 + 8 * g) ^ sb]);
            }
            f32x4 eacc[2][4];
#pragma unroll
            for (int mi = 0; mi < 2; ++mi)
#pragma unroll
                for (int nt = 0; nt < 4; ++nt) eacc[mi][nt] = (f32x4){0.f, 0.f, 0.f, 0.f};
#pragma unroll
            for (int mi = 0; mi < 2; ++mi)
#pragma unroll
                for (int kc = 0; kc < 4; ++kc)
#pragma unroll
                    for (int nt = 0; nt < 4; ++nt)
                        eacc[mi][nt] = __builtin_amdgcn_mfma_f32_16x16x32_f16(wa[mi][kc], bf[nt][kc], eacc[mi][nt], 0, 0, 0);
            float ps[4] = {0.f, 0.f, 0.f, 0.f};
#pragma unroll
            for (int mi = 0; mi < 2; ++mi)
#pragma unroll
                for (int nt = 0; nt < 4; ++nt)
#pragma unroll
                    for (int r = 0; r < 4; ++r) {
                        const float e = __expf(eacc[mi][nt][r]);
                        ps[nt] += e;
                        eacc[mi][nt][r] = e;
                    }
            float scn[4];
#pragma unroll
            for (int nt = 0; nt < 4; ++nt) {
                ps[nt] += __shfl_xor(ps[nt], 16);
                ps[nt] += __shfl_xor(ps[nt], 32);
                scn[nt] = SCALE_Q / ps[nt];
            }
#pragma unroll
            for (int mi = 0; mi < 2; ++mi)
#pragma unroll
                for (int nt = 0; nt < 4; ++nt) {
                    const int sb = ((4 * nt + (l15 >> 2)) & 7) << 3;
                    half4v p;
#pragma unroll
                    for (int r = 0; r < 4; ++r) p[r] = (_Float16)(eacc[mi][nt][r] * scn[nt]);
                    *(half4v*)(&qT[nt * 16 + l15][((w * 2 + mi) * 16 + g * 4) ^ sb]) = p;
                }
        }
        __syncthreads();   // (A) qT(Ê) ready; Xb reads done
        // stage tile it+1 into Xb (overlaps phase 3)
        if (it < TILES - 1) {
#pragma unroll
            for (int cc = 0; cc < 8; ++cc) {
                const int c = c0 + 16 * cc;
                Xb[4 * j4 + 0][c ^ sxw] = (_Float16)xr[cc].x;
                Xb[4 * j4 + 1][c ^ sxw] = (_Float16)xr[cc].y;
                Xb[4 * j4 + 2][c ^ sxw] = (_Float16)xr[cc].z;
                Xb[4 * j4 + 3][c ^ sxw] = (_Float16)xr[cc].w;
            }
        }
        // phase 3: y = G @ Ê + b_out -> f16 stash, + stats
        {
            half8 bf[4][4];
#pragma unroll
            for (int nt = 0; nt < 4; ++nt) {
                const int sb = ((4 * nt + (l15 >> 2)) & 7) << 3;
#pragma unroll
                for (int kc = 0; kc < 4; ++kc)
                    bf[nt][kc] = *(const half8*)(&qT[nt * 16 + l15][(kc * 32 + 8 * g) ^ sb]);
            }
#pragma unroll
            for (int mi = 0; mi < 2; ++mi) {
                const int o0 = (w * 2 + mi) * 16 + g * 4;
                f32x4 acc[4];
#pragma unroll
                for (int nt = 0; nt < 4; ++nt) acc[nt] = (f32x4){0.f, 0.f, 0.f, 0.f};
#pragma unroll
                for (int kc = 0; kc < 4; ++kc)
#pragma unroll
                    for (int nt = 0; nt < 4; ++nt)
                        acc[nt] = __builtin_amdgcn_mfma_f32_16x16x32_f16(ga[mi][kc], bf[nt][kc], acc[nt], 0, 0, 0);
                float bo[4];
#pragma unroll
                for (int r = 0; r < 4; ++r) bo[r] = b_out[o0 + r];
#pragma unroll
                for (int r = 0; r < 4; ++r) {
                    _Float16* yrow = (_Float16*)(ybase + (size_t)(b * DIMC + o0 + r) * 131072 + 65536);
#pragma unroll
                    for (int nt = 0; nt < 4; ++nt) {
                        const int jn = j0 + nt * 16 + l15;
                        const float yv = acc[nt][r] + bo[r];
                        ssum += yv;
                        ssq += yv * yv;
                        yrow[jn] = (_Float16)yv;
                    }
                }
            }
        }
        __syncthreads();   // (B) qT reads done before next iter's writes; Xb staged visible
    }
#pragma unroll
    for (int m = 32; m; m >>= 1) { ssum += __shfl_xor(ssum, m); ssq += __shfl_xor(ssq, m); }
    if (lane == 0) { red[w] = ssum; red[4 + w] = ssq; }
    __syncthreads();
    if (t == 0) {
        atomicAdd(&St[b * 2 + 0], red[0] + red[1] + red[2] + red[3]);
        atomicAdd(&St[b * 2 + 1], red[4] + red[5] + red[6] + red[7]);
    }
}

// ---------------- K4: layernorm; read f16 stash (2nd half of own row), write f32 ----------------
__global__ __launch_bounds__(256) void k4_norm(float* __restrict__ out, const float* __restrict__ St,
                                               const float* __restrict__ gamma,
                                               const float* __restrict__ beta) {
    const int o = blockIdx.x;
    const int b = blockIdx.y;
    const int t = threadIdx.x;
    const size_t row = (size_t)b * DIMC + o;
    const float n = (float)DIMC * (float)NTOT;
    const float mean = St[b * 2] / n;
    const float var = St[b * 2 + 1] / n - mean * mean;
    const float rs = rsqrtf(var + 1e-5f);
    const float ga = gamma[o] * rs;
    const float be = beta[o];
    const half8* yh = (const half8*)((const char*)out + row * 131072 + 65536);
    half8 hbuf[16];
#pragma unroll
    for (int i = 0; i < 16; ++i) hbuf[i] = yh[i * 256 + t];
    __syncthreads();  // all reads before any f32 overwrite (stash lives in this row)
    float4* orow = (float4*)(out + row * NTOT);
#pragma unroll
    for (int i = 0; i < 16; ++i) {
        const int e4 = (i * 256 + t) * 2;
        float4 v0, v1;
        v0.x = ((float)hbuf[i][0] - mean) * ga + be;
        v0.y = ((float)hbuf[i][1] - mean) * ga + be;
        v0.z = ((float)hbuf[i][2] - mean) * ga + be;
        v0.w = ((float)hbuf[i][3] - mean) * ga + be;
        v1.x = ((float)hbuf[i][4] - mean) * ga + be;
        v1.y = ((float)hbuf[i][5] - mean) * ga + be;
        v1.z = ((float)hbuf[i][6] - mean) * ga + be;
        v1.w = ((float)hbuf[i][7] - mean) * ga + be;
        orow[e4] = v0;
        orow[e4 + 1] = v1;
    }
}

extern "C" void kernel_launch(void* const* d_in, const int* in_sizes, int n_in,
                              void* d_out, int out_size, void* d_ws, size_t ws_size,
                              hipStream_t stream) {
    const float* x     = (const float*)d_in[0];
    const float* wqkv  = (const float*)d_in[1];
    const float* wout  = (const float*)d_in[2];
    const float* b_out = (const float*)d_in[3];
    const float* gamma = (const float*)d_in[4];
    const float* beta  = (const float*)d_in[5];
    if (ws_size < WS_NEED) return;
    char* ws = (char*)d_ws;
    _Float16* Wb = (_Float16*)(ws + WS_WQKV);
    float* S  = (float*)(ws + WS_S);
    float* Z  = (float*)(ws + WS_Z);
    float* St = (float*)(ws + WS_ST);

    k0_prep<<<325, 256, 0, stream>>>(wqkv, ws);
    k1_kv<<<dim3(GRIDX, 8), 256, 0, stream>>>(x, Wb, S, Z);
    k2_g<<<dim3(HEADS, 8), 256, 0, stream>>>(S, Z, wout, (char*)d_out);
    k3_main<<<dim3(GRIDX, 8), 256, 0, stream>>>(x, Wb, b_out, (char*)d_out, St);
    k4_norm<<<dim3(128, 8), 256, 0, stream>>>((float*)d_out, St, gamma, beta);
}